// Round 6
// baseline (229.603 us; speedup 1.0000x reference)
//
#include <hip/hip_runtime.h>
#include <hip/hip_bf16.h>

// MoE PHM MLP, MI355X. B=2,S=2048,D=1024 -> T=4096 tokens; E=8, N=4, HID=4096.
// router(f64, writes bf16 x copy) -> plan -> W_eff materialization (bf16) ->
// fc GEMM (+leaky^2) -> proj GEMM (split-K=2 -> f32 partials) -> reduce.
// GEMM: 512 thr / 8 waves (2Mx4N), BM=128 BN=256 BK=64, ring-3 LDS (144KB),
// counted s_waitcnt vmcnt(6) + raw s_barrier (loads stay in flight across
// barriers, AITER/T4 pattern), XOR-swizzled LDS via pre-swizzled global src.
//
// Workspace (~187 MiB, same layout as r5):
//   [0,64MiB)    W_fc bf16 [E][4096][1024]; dead after fc -> proj f32 partials
//   [64,128MiB)  W_proj bf16 [E][1024][4096]
//   xb bf16 [4096][1024], h bf16 [5120][4096], probs, eidx, tok, counts

#define T_TOK 4096
#define DIM   1024
#define NEXP  8
#define HIDD  4096
#define SLOTS 5120

static constexpr size_t OFF_WFC   = 0;
static constexpr size_t OFF_WPROJ = 67108864ull;
static constexpr size_t OFF_XB    = 134217728ull;
static constexpr size_t OFF_H     = 144703488ull;
static constexpr size_t OFF_PROBS = 186646528ull;
static constexpr size_t OFF_EIDX  = OFF_PROBS + (size_t)T_TOK*8*4;
static constexpr size_t OFF_TOK   = OFF_EIDX + (size_t)T_TOK*4;
static constexpr size_t OFF_CNT   = OFF_TOK + (size_t)SLOTS*4;

typedef __attribute__((ext_vector_type(8))) short short8;
typedef __attribute__((ext_vector_type(4))) float f32x4;

static __device__ __forceinline__ ushort f2bf(float f) {
    __hip_bfloat16 h = __float2bfloat16(f);
    return __builtin_bit_cast(ushort, h);
}

static __device__ __forceinline__ void gload_lds16(const ushort* g, ushort* l) {
    __builtin_amdgcn_global_load_lds((const __attribute__((address_space(1))) void*)g,
                                     (__attribute__((address_space(3))) void*)l,
                                     16, 0, 0);
}

// ------- router: f64 logits, softmax probs, argmax, bf16 x copy (token order)
__global__ __launch_bounds__(256) void router_k(const float* __restrict__ x,
                                                const float* __restrict__ wr,
                                                float* __restrict__ probs,
                                                int* __restrict__ eidx,
                                                ushort* __restrict__ xb)
{
    int tid = threadIdx.x, w = tid >> 6, lane = tid & 63;
    int t = blockIdx.x * 4 + w;
    const float4* xr = (const float4*)(x + (size_t)t * DIM);
    float4 xv[4];
#pragma unroll
    for (int q = 0; q < 4; q++) xv[q] = xr[q * 64 + lane];
    ushort4* xo = (ushort4*)(xb + (size_t)t * DIM);
#pragma unroll
    for (int q = 0; q < 4; q++) {
        float4 v = xv[q];
        ushort4 bq;
        bq.x = f2bf(v.x); bq.y = f2bf(v.y); bq.z = f2bf(v.z); bq.w = f2bf(v.w);
        xo[q * 64 + lane] = bq;
    }
    double lg[8];
#pragma unroll
    for (int e = 0; e < 8; e++) {
        const float4* wv = (const float4*)(wr + (size_t)e * DIM);
        double s = 0.0;
#pragma unroll
        for (int q = 0; q < 4; q++) {
            float4 a = xv[q], b = wv[q * 64 + lane];
            s += (double)a.x * b.x + (double)a.y * b.y + (double)a.z * b.z + (double)a.w * b.w;
        }
#pragma unroll
        for (int d = 1; d < 64; d <<= 1) s += __shfl_xor(s, d);
        lg[e] = s;
    }
    double m = lg[0];
#pragma unroll
    for (int e = 1; e < 8; e++) m = lg[e] > m ? lg[e] : m;
    double ex[8], sum = 0.0;
#pragma unroll
    for (int e = 0; e < 8; e++) { ex[e] = exp(lg[e] - m); sum += ex[e]; }
    if (lane < 8) probs[(size_t)t * 8 + lane] = (float)(ex[lane] / sum);
    if (lane == 0) {
        int am = 0; double bv = lg[0];
#pragma unroll
        for (int e = 1; e < 8; e++) if (lg[e] > bv) { bv = lg[e]; am = e; }  // first-max = jnp.argmax
        eidx[t] = am;
    }
}

// --- plan: single block. tok=-1 init, histogram, stable rank, offsets, aux ---
__global__ __launch_bounds__(256) void plan_k(const float* __restrict__ probs,
                                              const int* __restrict__ eidx,
                                              int* __restrict__ counts,
                                              int* __restrict__ offsets,
                                              int* __restrict__ tok,
                                              float* __restrict__ auxout)
{
    __shared__ int hist[256][8];
    __shared__ double red[256][8];
    __shared__ int offs[8];
    int tid = threadIdx.x;
    for (int i = tid; i < SLOTS; i += 256) tok[i] = -1;
    int base = tid * 16;
    int le[16];
    int lc[8] = {0,0,0,0,0,0,0,0};
#pragma unroll
    for (int j = 0; j < 16; j++) { le[j] = eidx[base + j]; lc[le[j]]++; }
#pragma unroll
    for (int e = 0; e < 8; e++) hist[tid][e] = lc[e];
    __syncthreads();
    for (int s = 1; s < 256; s <<= 1) {
        int v[8];
        if (tid >= s) {
#pragma unroll
            for (int e = 0; e < 8; e++) v[e] = hist[tid - s][e];
        }
        __syncthreads();
        if (tid >= s) {
#pragma unroll
            for (int e = 0; e < 8; e++) hist[tid][e] += v[e];
        }
        __syncthreads();
    }
    int myBase[8];
#pragma unroll
    for (int e = 0; e < 8; e++) myBase[e] = hist[tid][e] - lc[e];
    if (tid == 0) {
        int off = 0;
#pragma unroll
        for (int e = 0; e < 8; e++) {
            int c = hist[255][e];
            counts[e] = c;
            offsets[e] = off; offs[e] = off;
            off += (c + 127) & ~127;
        }
    }
    __syncthreads();
    int cur[8];
#pragma unroll
    for (int e = 0; e < 8; e++) cur[e] = myBase[e];
#pragma unroll
    for (int j = 0; j < 16; j++) {
        int e = le[j];
        tok[offs[e] + cur[e]++] = base + j;
    }
    double ps[8] = {0, 0, 0, 0, 0, 0, 0, 0};
    for (int t = tid; t < T_TOK; t += 256) {
#pragma unroll
        for (int e = 0; e < 8; e++) ps[e] += (double)probs[(size_t)t * 8 + e];
    }
#pragma unroll
    for (int e = 0; e < 8; e++) red[tid][e] = ps[e];
    __syncthreads();
    for (int s = 128; s > 0; s >>= 1) {
        if (tid < s) {
#pragma unroll
            for (int e = 0; e < 8; e++) red[tid][e] += red[tid + s][e];
        }
        __syncthreads();
    }
    if (tid == 0) {
        double aux = 0.0;
#pragma unroll
        for (int e = 0; e < 8; e++)
            aux += ((double)hist[255][e] / T_TOK) * (red[0][e] / T_TOK);
        auxout[0] = (float)(aux * NEXP);
    }
}

// -------- materialize W_fc[e][j*1024+o][k*256+l] = sum_i A[i,j,k]*S[i,o,l] ---
__global__ __launch_bounds__(256) void wfc_k(const float* __restrict__ A,
                                             const float* __restrict__ S,
                                             ushort* __restrict__ W)
{
    int b = blockIdx.x;
    int e = b >> 10, o = b & 1023;
    int l = threadIdx.x;
    __shared__ float Ash[64];
    if (l < 64) Ash[l] = A[e * 64 + l];
    __syncthreads();
    float s0 = S[((size_t)(e * 4 + 0) * 1024 + o) * 256 + l];
    float s1 = S[((size_t)(e * 4 + 1) * 1024 + o) * 256 + l];
    float s2 = S[((size_t)(e * 4 + 2) * 1024 + o) * 256 + l];
    float s3 = S[((size_t)(e * 4 + 3) * 1024 + o) * 256 + l];
    size_t base = (size_t)e * 4194304ull;
#pragma unroll
    for (int j = 0; j < 4; j++)
#pragma unroll
        for (int k = 0; k < 4; k++) {
            float v = Ash[j * 4 + k] * s0 + Ash[16 + j * 4 + k] * s1 +
                      Ash[32 + j * 4 + k] * s2 + Ash[48 + j * 4 + k] * s3;
            W[base + (size_t)(j * 1024 + o) * 1024 + k * 256 + l] = f2bf(v);
        }
}

// ------- materialize W_proj[e][j*256+o][k*1024+l] = sum_i A[i,j,k]*S[i,o,l] --
__global__ __launch_bounds__(256) void wpj_k(const float* __restrict__ A,
                                             const float* __restrict__ S,
                                             ushort* __restrict__ W)
{
    int b = blockIdx.x;
    int e = b >> 8, o = b & 255;
    int tid = threadIdx.x;
    __shared__ float Ash[64];
    if (tid < 64) Ash[tid] = A[e * 64 + tid];
    __syncthreads();
    float s[4][4];
#pragma unroll
    for (int i = 0; i < 4; i++)
#pragma unroll
        for (int q = 0; q < 4; q++)
            s[i][q] = S[((size_t)(e * 4 + i) * 256 + o) * 1024 + q * 256 + tid];
    size_t base = (size_t)e * 4194304ull;
#pragma unroll
    for (int j = 0; j < 4; j++)
#pragma unroll
        for (int k = 0; k < 4; k++) {
            float a0 = Ash[j * 4 + k], a1 = Ash[16 + j * 4 + k];
            float a2 = Ash[32 + j * 4 + k], a3 = Ash[48 + j * 4 + k];
#pragma unroll
            for (int q = 0; q < 4; q++) {
                float v = a0 * s[0][q] + a1 * s[1][q] + a2 * s[2][q] + a3 * s[3][q];
                W[base + (size_t)(j * 256 + o) * 4096 + k * 1024 + q * 256 + tid] = f2bf(v);
            }
        }
}

// ---------------- MFMA GEMM: C[m,n] = sum_k A[m,k] * W[n,k]  (B^T layout) ----
// 512 thr / 8 waves (wm=w>>2, wn=w&3; per-wave 64x64 out, acc 4x4), BM=128,
// BN=256, BK=64. Ring-3 LDS (A 3x16KB + B 3x32KB = 144KB), prefetch depth 2,
// counted vmcnt(6) + raw s_barrier per K-tile (never drains to 0 mid-loop).
// XOR-swizzle on global source chunk + same XOR on ds_read (rule 21).
template <int KDIM, int NDIM, int NSPLIT, bool FC>
__global__ __launch_bounds__(512, 4) void moe_gemm_k(const ushort* __restrict__ Abuf,
                                                     const ushort* __restrict__ Wbuf,
                                                     ushort* __restrict__ Hout,
                                                     float* __restrict__ Yout,
                                                     const int* __restrict__ counts,
                                                     const int* __restrict__ offsets,
                                                     const int* __restrict__ tok)
{
    __shared__ __align__(16) ushort As[3][128 * 64];
    __shared__ __align__(16) ushort Bs[3][256 * 64];
    constexpr int KSUB = KDIM / NSPLIT;
    constexpr int NT = KSUB / 64;
    int b = blockIdx.x;
    int nb, split, ms;
    if (FC) {               // grid 640: 16 n-panels, 2 per XCD
        int r = b >> 3;
        nb = (b & 7) * 2 + r / 40;
        split = 0;
        ms = r % 40;
    } else {                // grid 320: 4 n-panels x 2 splits = 8 combos = XCD
        nb = (b & 7) >> 1;
        split = b & 1;
        ms = b >> 3;
    }
    int e = -1, mt = 0, acct = 0;
#pragma unroll
    for (int i = 0; i < 8; i++) {
        int tiles = (counts[i] + 127) >> 7;
        if (e < 0 && ms < acct + tiles) { e = i; mt = ms - acct; }
        acct += tiles;
    }
    if (e < 0) return;
    int m_base = offsets[e] + mt * 128;
    int n_base = nb * 256;
    int tid = threadIdx.x, w = tid >> 6, lane = tid & 63;
    int wm = w >> 2, wn = w & 3;
    const ushort* Bb = Wbuf + (size_t)e * NDIM * KDIM + (size_t)n_base * KDIM;
    int lr = lane >> 3;                        // staging row within 8-row group
    int lcs = (((lane & 7) ^ lr) << 3);        // swizzled source chunk (ushorts)
    int kbase = split * KSUB;
    // per-instr global row pointers (fixed across K)
    const ushort* arow[2];
#pragma unroll
    for (int i = 0; i < 2; i++) {
        int sl = m_base + i * 64 + w * 8 + lr;
        int rt = sl;
        if (FC) { rt = tok[sl]; if (rt < 0) rt = 0; }
        arow[i] = Abuf + (size_t)rt * KDIM + kbase + lcs;
    }
    const ushort* brow[4];
#pragma unroll
    for (int i = 0; i < 4; i++)
        brow[i] = Bb + (size_t)(i * 64 + w * 8 + lr) * KDIM + kbase + lcs;

    f32x4 acc[4][4];
#pragma unroll
    for (int i = 0; i < 4; i++)
#pragma unroll
        for (int j = 0; j < 4; j++) acc[i][j] = (f32x4){0.f, 0.f, 0.f, 0.f};

    auto STAGE = [&](int kt, int q) {
        int k0 = kt * 64;
#pragma unroll
        for (int i = 0; i < 2; i++)
            gload_lds16(arow[i] + k0, &As[q][(i * 64 + w * 8) * 64]);
#pragma unroll
        for (int i = 0; i < 4; i++)
            gload_lds16(brow[i] + k0, &Bs[q][(i * 64 + w * 8) * 64]);
    };

    // prologue: stage tiles 0,1 -> 12 loads in flight per wave
    STAGE(0, 0);
    STAGE(1, 1);

    int q = 0;
    for (int t = 0; t < NT; t++) {
        // publish tile t: wait for the oldest 6 loads (tile t's), keep tile
        // t+1's 6 in flight across the barrier (T4 counted-vmcnt pattern)
        if (t == NT - 1) { asm volatile("s_waitcnt vmcnt(0)" ::: "memory"); }
        else             { asm volatile("s_waitcnt vmcnt(6)" ::: "memory"); }
        __builtin_amdgcn_s_barrier();
        __builtin_amdgcn_sched_barrier(0);   // pin ds_reads below the barrier
        if (t + 2 < NT) STAGE(t + 2, (q + 2) % 3);
#pragma unroll
        for (int ks = 0; ks < 2; ks++) {
            short8 a[4], bb[4];
            int ca = (((ks * 4 + (lane >> 4)) ^ (lane & 7)) << 3);
#pragma unroll
            for (int f = 0; f < 4; f++) {
                a[f]  = *(const short8*)&As[q][(wm * 64 + f * 16 + (lane & 15)) * 64 + ca];
                bb[f] = *(const short8*)&Bs[q][(wn * 64 + f * 16 + (lane & 15)) * 64 + ca];
            }
            __builtin_amdgcn_s_setprio(1);
#pragma unroll
            for (int mf = 0; mf < 4; mf++)
#pragma unroll
                for (int nf = 0; nf < 4; nf++)
                    acc[mf][nf] = __builtin_amdgcn_mfma_f32_16x16x32_bf16(a[mf], bb[nf], acc[mf][nf], 0, 0, 0);
            __builtin_amdgcn_s_setprio(0);
        }
        // all waves done reading buf q before anyone stages into it (next iters)
        __builtin_amdgcn_s_barrier();
        q = (q + 1) % 3;
    }

    int col0 = n_base + wn * 64;
    int row0 = wm * 64 + (lane >> 4) * 4;   // C/D: col=lane&15, row=(lane>>4)*4+reg
    if (FC) {
#pragma unroll
        for (int mf = 0; mf < 4; mf++)
#pragma unroll
            for (int nf = 0; nf < 4; nf++) {
                int col = col0 + nf * 16 + (lane & 15);
#pragma unroll
                for (int rg = 0; rg < 4; rg++) {
                    float v = acc[mf][nf][rg];
                    v = v >= 0.f ? v : 0.5f * v;   // leaky relu slope 0.5
                    v = v * v;                     // square
                    Hout[(size_t)(m_base + row0 + mf * 16 + rg) * NDIM + col] = f2bf(v);
                }
            }
    } else {
        float* P = Yout + (size_t)split * SLOTS * NDIM;
#pragma unroll
        for (int mf = 0; mf < 4; mf++)
#pragma unroll
            for (int nf = 0; nf < 4; nf++) {
                int col = col0 + nf * 16 + (lane & 15);
#pragma unroll
                for (int rg = 0; rg < 4; rg++)
                    P[(size_t)(m_base + row0 + mf * 16 + rg) * NDIM + col] = acc[mf][nf][rg];
            }
    }
}

// -------- reduce: out[tok[slot]] = P0[slot] + P1[slot] (valid slots) ---------
__global__ __launch_bounds__(256) void reduce_k(const float* __restrict__ P,
                                                const int* __restrict__ tok,
                                                float* __restrict__ out)
{
    int slot = blockIdx.x;
    int t = tok[slot];
    if (t < 0) return;
    const float4* p0 = (const float4*)(P + (size_t)slot * DIM);
    const float4* p1 = (const float4*)(P + (size_t)(SLOTS + slot) * DIM);
    float4* o = (float4*)(out + (size_t)t * DIM);
    int i = threadIdx.x;
    float4 a = p0[i], b = p1[i];
    o[i] = (float4){a.x + b.x, a.y + b.y, a.z + b.z, a.w + b.w};
}

extern "C" void kernel_launch(void* const* d_in, const int* in_sizes, int n_in,
                              void* d_out, int out_size, void* d_ws, size_t ws_size,
                              hipStream_t stream)
{
    const float* x    = (const float*)d_in[0];
    const float* wr   = (const float*)d_in[1];
    const float* A_fc = (const float*)d_in[2];
    const float* S_fc = (const float*)d_in[3];
    const float* A_pj = (const float*)d_in[4];
    const float* S_pj = (const float*)d_in[5];
    float* out = (float*)d_out;
    char* ws = (char*)d_ws;

    ushort* Wfc   = (ushort*)(ws + OFF_WFC);
    float*  Part  = (float*)(ws + OFF_WFC);    // aliases W_fc (dead after fc GEMM)
    ushort* Wpj   = (ushort*)(ws + OFF_WPROJ);
    ushort* xb    = (ushort*)(ws + OFF_XB);
    ushort* h     = (ushort*)(ws + OFF_H);
    float*  probs = (float*)(ws + OFF_PROBS);
    int*    eidx  = (int*)(ws + OFF_EIDX);
    int*    tok   = (int*)(ws + OFF_TOK);
    int*    counts  = (int*)(ws + OFF_CNT);
    int*    offsets = counts + 16;

    router_k<<<T_TOK / 4, 256, 0, stream>>>(x, wr, probs, eidx, xb);
    plan_k<<<1, 256, 0, stream>>>(probs, eidx, counts, offsets, tok,
                                  out + (size_t)T_TOK * DIM);
    wfc_k<<<NEXP * 1024, 256, 0, stream>>>(A_fc, S_fc, Wfc);
    wpj_k<<<NEXP * 256, 256, 0, stream>>>(A_pj, S_pj, Wpj);
    // fc: 40 m-tiles x 16 n-panels -> 640 blocks of 512 thr, indirect A
    moe_gemm_k<1024, 4096, 1, true><<<640, 512, 0, stream>>>(xb, Wfc, h, nullptr, counts, offsets, tok);
    // proj: 40 m-tiles x 4 n-panels x split-K 2 -> 320 blocks, f32 partials
    moe_gemm_k<4096, 1024, 2, false><<<320, 512, 0, stream>>>(h, Wpj, nullptr, Part, counts, offsets, tok);
    reduce_k<<<SLOTS, 256, 0, stream>>>(Part, tok, out);
}

// Round 7
// 195.290 us; speedup vs baseline: 1.1757x; 1.1757x over previous
//
#include <hip/hip_runtime.h>
#include <hip/hip_bf16.h>

// MoE PHM MLP, MI355X. B=2,S=2048,D=1024 -> T=4096 tokens; E=8, N=4, HID=4096.
// router(f64, emits bf16 x copy + per-block prob partial sums) -> plan ->
// W_eff materialization (merged wfc+wpj) -> fc GEMM (128x256, indirect A via
// tok[], epilogue leaky^2) -> proj GEMM (64x256, direct scatter to out).
// GEMMs: m97 2-barrier single-buffer structure, XOR-swizzled LDS via
// pre-swizzled global source (bank conflicts measured 0), XCD-aware decode.
//
// Workspace (~187 MiB):
//   [0,64MiB)    W_fc bf16 [E][4096][1024]
//   [64,128MiB)  W_proj bf16 [E][1024][4096]
//   xb bf16 [4096][1024], h bf16 [5120][4096], bsum f64[1024][8],
//   eidx int[T], tok int[5120], counts/offsets

#define T_TOK 4096
#define DIM   1024
#define NEXP  8
#define HIDD  4096
#define SLOTS 5120

static constexpr size_t OFF_WFC   = 0;
static constexpr size_t OFF_WPROJ = 67108864ull;
static constexpr size_t OFF_XB    = 134217728ull;
static constexpr size_t OFF_H     = 144703488ull;
static constexpr size_t OFF_BSUM  = 186646528ull;                     // 64 KB
static constexpr size_t OFF_EIDX  = OFF_BSUM + 1024*8*8;
static constexpr size_t OFF_TOK   = OFF_EIDX + (size_t)T_TOK*4;
static constexpr size_t OFF_CNT   = OFF_TOK + (size_t)SLOTS*4;

typedef __attribute__((ext_vector_type(8))) short short8;
typedef __attribute__((ext_vector_type(4))) float f32x4;

static __device__ __forceinline__ ushort f2bf(float f) {
    __hip_bfloat16 h = __float2bfloat16(f);
    return __builtin_bit_cast(ushort, h);
}

static __device__ __forceinline__ void gload_lds16(const ushort* g, ushort* l) {
    __builtin_amdgcn_global_load_lds((const __attribute__((address_space(1))) void*)g,
                                     (__attribute__((address_space(3))) void*)l,
                                     16, 0, 0);
}

// --- router: f64 logits, argmax, bf16 x copy, per-block 8xf64 prob sums -----
__global__ __launch_bounds__(256) void router_k(const float* __restrict__ x,
                                                const float* __restrict__ wr,
                                                double* __restrict__ bsum,
                                                int* __restrict__ eidx,
                                                ushort* __restrict__ xb)
{
    __shared__ double shp[4][8];
    int tid = threadIdx.x, w = tid >> 6, lane = tid & 63;
    int t = blockIdx.x * 4 + w;
    const float4* xr = (const float4*)(x + (size_t)t * DIM);
    float4 xv[4];
#pragma unroll
    for (int q = 0; q < 4; q++) xv[q] = xr[q * 64 + lane];
    ushort4* xo = (ushort4*)(xb + (size_t)t * DIM);
#pragma unroll
    for (int q = 0; q < 4; q++) {
        float4 v = xv[q];
        ushort4 bq;
        bq.x = f2bf(v.x); bq.y = f2bf(v.y); bq.z = f2bf(v.z); bq.w = f2bf(v.w);
        xo[q * 64 + lane] = bq;
    }
    double lg[8];
#pragma unroll
    for (int e = 0; e < 8; e++) {
        const float4* wv = (const float4*)(wr + (size_t)e * DIM);
        double s = 0.0;
#pragma unroll
        for (int q = 0; q < 4; q++) {
            float4 a = xv[q], b = wv[q * 64 + lane];
            s += (double)a.x * b.x + (double)a.y * b.y + (double)a.z * b.z + (double)a.w * b.w;
        }
#pragma unroll
        for (int d = 1; d < 64; d <<= 1) s += __shfl_xor(s, d);
        lg[e] = s;
    }
    double m = lg[0];
#pragma unroll
    for (int e = 1; e < 8; e++) m = lg[e] > m ? lg[e] : m;
    double ex[8], sum = 0.0;
#pragma unroll
    for (int e = 0; e < 8; e++) { ex[e] = exp(lg[e] - m); sum += ex[e]; }
    if (lane < 8) shp[w][lane] = ex[lane] / sum;
    if (lane == 0) {
        int am = 0; double bv = lg[0];
#pragma unroll
        for (int e = 1; e < 8; e++) if (lg[e] > bv) { bv = lg[e]; am = e; }  // first-max = jnp.argmax
        eidx[t] = am;
    }
    __syncthreads();
    if (tid < 8)
        bsum[(size_t)blockIdx.x * 8 + tid] =
            shp[0][tid] + shp[1][tid] + shp[2][tid] + shp[3][tid];
}

// --- plan: single block. tok=-1 init, histogram, stable rank, offsets, aux ---
__global__ __launch_bounds__(256) void plan_k(const double* __restrict__ bsum,
                                              const int* __restrict__ eidx,
                                              int* __restrict__ counts,
                                              int* __restrict__ offsets,
                                              int* __restrict__ tok,
                                              float* __restrict__ auxout)
{
    __shared__ int hist[256][8];
    __shared__ double red[256][8];
    __shared__ int offs[8];
    int tid = threadIdx.x;
    for (int i = tid; i < SLOTS; i += 256) tok[i] = -1;
    int base = tid * 16;
    int le[16];
    int lc[8] = {0,0,0,0,0,0,0,0};
#pragma unroll
    for (int j = 0; j < 16; j++) { le[j] = eidx[base + j]; lc[le[j]]++; }
#pragma unroll
    for (int e = 0; e < 8; e++) hist[tid][e] = lc[e];
    __syncthreads();
    for (int s = 1; s < 256; s <<= 1) {
        int v[8];
        if (tid >= s) {
#pragma unroll
            for (int e = 0; e < 8; e++) v[e] = hist[tid - s][e];
        }
        __syncthreads();
        if (tid >= s) {
#pragma unroll
            for (int e = 0; e < 8; e++) hist[tid][e] += v[e];
        }
        __syncthreads();
    }
    int myBase[8];
#pragma unroll
    for (int e = 0; e < 8; e++) myBase[e] = hist[tid][e] - lc[e];
    if (tid == 0) {
        int off = 0;
#pragma unroll
        for (int e = 0; e < 8; e++) {
            int c = hist[255][e];
            counts[e] = c;
            offsets[e] = off; offs[e] = off;
            off += (c + 127) & ~127;
        }
    }
    __syncthreads();
    int cur[8];
#pragma unroll
    for (int e = 0; e < 8; e++) cur[e] = myBase[e];
#pragma unroll
    for (int j = 0; j < 16; j++) {
        int e = le[j];
        tok[offs[e] + cur[e]++] = base + j;
    }
    // aux from per-block partial sums (1024 blocks x 8)
    double ps[8] = {0, 0, 0, 0, 0, 0, 0, 0};
    for (int b = tid; b < 1024; b += 256) {
#pragma unroll
        for (int e = 0; e < 8; e++) ps[e] += bsum[(size_t)b * 8 + e];
    }
#pragma unroll
    for (int e = 0; e < 8; e++) red[tid][e] = ps[e];
    __syncthreads();
    for (int s = 128; s > 0; s >>= 1) {
        if (tid < s) {
#pragma unroll
            for (int e = 0; e < 8; e++) red[tid][e] += red[tid + s][e];
        }
        __syncthreads();
    }
    if (tid == 0) {
        double aux = 0.0;
#pragma unroll
        for (int e = 0; e < 8; e++)
            aux += ((double)hist[255][e] / T_TOK) * (red[0][e] / T_TOK);
        auxout[0] = (float)(aux * NEXP);
    }
}

// --- merged W materialization: blocks [0,8192) = W_fc, [8192,10240) = W_proj
__global__ __launch_bounds__(256) void wmat_k(const float* __restrict__ Afc,
                                              const float* __restrict__ Sfc,
                                              const float* __restrict__ Apj,
                                              const float* __restrict__ Spj,
                                              ushort* __restrict__ Wfc,
                                              ushort* __restrict__ Wpj)
{
    __shared__ float Ash[64];
    int b = blockIdx.x;
    int tid = threadIdx.x;
    if (b < 8192) {
        int e = b >> 10, o = b & 1023;
        if (tid < 64) Ash[tid] = Afc[e * 64 + tid];
        __syncthreads();
        float s0 = Sfc[((size_t)(e * 4 + 0) * 1024 + o) * 256 + tid];
        float s1 = Sfc[((size_t)(e * 4 + 1) * 1024 + o) * 256 + tid];
        float s2 = Sfc[((size_t)(e * 4 + 2) * 1024 + o) * 256 + tid];
        float s3 = Sfc[((size_t)(e * 4 + 3) * 1024 + o) * 256 + tid];
        size_t base = (size_t)e * 4194304ull;
#pragma unroll
        for (int j = 0; j < 4; j++)
#pragma unroll
            for (int k = 0; k < 4; k++) {
                float v = Ash[j * 4 + k] * s0 + Ash[16 + j * 4 + k] * s1 +
                          Ash[32 + j * 4 + k] * s2 + Ash[48 + j * 4 + k] * s3;
                Wfc[base + (size_t)(j * 1024 + o) * 1024 + k * 256 + tid] = f2bf(v);
            }
    } else {
        int b2 = b - 8192;
        int e = b2 >> 8, o = b2 & 255;
        if (tid < 64) Ash[tid] = Apj[e * 64 + tid];
        __syncthreads();
        float s[4][4];
#pragma unroll
        for (int i = 0; i < 4; i++)
#pragma unroll
            for (int q = 0; q < 4; q++)
                s[i][q] = Spj[((size_t)(e * 4 + i) * 256 + o) * 1024 + q * 256 + tid];
        size_t base = (size_t)e * 4194304ull;
#pragma unroll
        for (int j = 0; j < 4; j++)
#pragma unroll
            for (int k = 0; k < 4; k++) {
                float a0 = Ash[j * 4 + k], a1 = Ash[16 + j * 4 + k];
                float a2 = Ash[32 + j * 4 + k], a3 = Ash[48 + j * 4 + k];
#pragma unroll
                for (int q = 0; q < 4; q++) {
                    float v = a0 * s[0][q] + a1 * s[1][q] + a2 * s[2][q] + a3 * s[3][q];
                    Wpj[base + (size_t)(j * 256 + o) * 4096 + k * 1024 + q * 256 + tid] = f2bf(v);
                }
            }
    }
}

// ---------------- MFMA GEMM: C[m,n] = sum_k A[m,k] * W[n,k]  (B^T layout) ----
// m97 2-barrier single-buffer structure, BK=64, 4 waves, XOR-swizzled LDS.
// FC:  BM=128, BN=256, waves 2Mx2N (per-wave 64x128, acc 4x8), A via tok[],
//      epilogue leaky(0.5)^2 -> h bf16. Grid 640 (16 n-panels, XCD-grouped).
// !FC: BM=64, BN=256, waves 1Mx4N (per-wave 64x64, acc 4x4), A = h rows,
//      epilogue: direct f32 scatter to out[tok[slot]] (each (slot,col) has
//      exactly one writer -> no atomics, no split-K, no reduce). Grid 320.
template <int KDIM, int NDIM, int BM, bool FC>
__global__ __launch_bounds__(256, 2) void moe_gemm_k(const ushort* __restrict__ Abuf,
                                                     const ushort* __restrict__ Wbuf,
                                                     ushort* __restrict__ Hout,
                                                     float* __restrict__ Yout,
                                                     const int* __restrict__ counts,
                                                     const int* __restrict__ offsets,
                                                     const int* __restrict__ tok)
{
    __shared__ __align__(16) ushort As[BM * 64];
    __shared__ __align__(16) ushort Bs[256 * 64];
    constexpr int NT = KDIM / 64;
    constexpr int NF = FC ? 8 : 4;          // acc n-frags per wave
    constexpr int WNC = FC ? 128 : 64;      // per-wave col span
    int b = blockIdx.x;
    int nb, ms;
    if (FC) {               // 640 blocks: 16 n-panels, 2 per XCD
        int r = b >> 3;
        nb = (b & 7) * 2 + r / 40;
        ms = r % 40;
    } else {                // 320 blocks: 4 n-panels x 80 m-slots
        nb = b & 3;
        ms = b >> 2;
    }
    int e = -1, mt = 0, acct = 0;
#pragma unroll
    for (int i = 0; i < 8; i++) {
        int tiles = (counts[i] + BM - 1) / BM;
        if (e < 0 && ms < acct + tiles) { e = i; mt = ms - acct; }
        acct += tiles;
    }
    if (e < 0) return;
    int m_base = offsets[e] + mt * BM;
    int n_base = nb * 256;
    int tid = threadIdx.x, w = tid >> 6, lane = tid & 63;
    int wm = FC ? (w >> 1) : 0;
    int wn = FC ? (w & 1) : w;
    const ushort* Bb = Wbuf + (size_t)e * NDIM * KDIM + (size_t)n_base * KDIM;
    int lr = lane >> 3;                        // staging row within 8-row group
    int lcs = (((lane & 7) ^ lr) << 3);        // swizzled source chunk (ushorts)
    // per-instr global A-row pointers (fixed across K); fc indirects via tok[]
    const ushort* arow[BM / 32];
#pragma unroll
    for (int i = 0; i < BM / 32; i++) {
        int sl = m_base + i * 32 + w * 8 + lr;
        int rt = sl;
        if (FC) { rt = tok[sl]; if (rt < 0) rt = 0; }
        arow[i] = Abuf + (size_t)rt * KDIM + lcs;
    }
    f32x4 acc[4][NF];
#pragma unroll
    for (int i = 0; i < 4; i++)
#pragma unroll
        for (int j = 0; j < NF; j++) acc[i][j] = (f32x4){0.f, 0.f, 0.f, 0.f};

    for (int t = 0; t < NT; t++) {
        int k0 = t * 64;
#pragma unroll
        for (int i = 0; i < BM / 32; i++)
            gload_lds16(arow[i] + k0, &As[(i * 32 + w * 8) * 64]);
#pragma unroll
        for (int i = 0; i < 8; i++) {
            int r0 = i * 32 + w * 8;
            gload_lds16(Bb + (size_t)(r0 + lr) * KDIM + k0 + lcs, &Bs[r0 * 64]);
        }
        __syncthreads();
#pragma unroll
        for (int ks = 0; ks < 2; ks++) {
            short8 a[4], bfr[NF];
            int ca = (((ks * 4 + (lane >> 4)) ^ (lane & 7)) << 3);
#pragma unroll
            for (int f = 0; f < 4; f++)
                a[f] = *(const short8*)&As[(wm * 64 + f * 16 + (lane & 15)) * 64 + ca];
#pragma unroll
            for (int f = 0; f < NF; f++)
                bfr[f] = *(const short8*)&Bs[(wn * WNC + f * 16 + (lane & 15)) * 64 + ca];
#pragma unroll
            for (int mf = 0; mf < 4; mf++)
#pragma unroll
                for (int nf = 0; nf < NF; nf++)
                    acc[mf][nf] = __builtin_amdgcn_mfma_f32_16x16x32_bf16(a[mf], bfr[nf], acc[mf][nf], 0, 0, 0);
        }
        __syncthreads();
    }

    int col0 = n_base + wn * WNC;
    int row0 = wm * 64 + (lane >> 4) * 4;   // C/D: col=lane&15, row=(lane>>4)*4+reg
    if (FC) {
#pragma unroll
        for (int mf = 0; mf < 4; mf++)
#pragma unroll
            for (int nf = 0; nf < NF; nf++) {
                int col = col0 + nf * 16 + (lane & 15);
#pragma unroll
                for (int rg = 0; rg < 4; rg++) {
                    float v = acc[mf][nf][rg];
                    v = v >= 0.f ? v : 0.5f * v;   // leaky relu slope 0.5
                    v = v * v;                     // square
                    Hout[(size_t)(m_base + row0 + mf * 16 + rg) * NDIM + col] = f2bf(v);
                }
            }
    } else {
        int limit = offsets[e] + counts[e];
#pragma unroll
        for (int mf = 0; mf < 4; mf++) {
            int tk[4]; bool vld[4];
#pragma unroll
            for (int rg = 0; rg < 4; rg++) {
                int slot = m_base + row0 + mf * 16 + rg;
                vld[rg] = slot < limit;
                tk[rg] = vld[rg] ? tok[slot] : 0;
            }
#pragma unroll
            for (int nf = 0; nf < NF; nf++) {
                int col = col0 + nf * 16 + (lane & 15);
#pragma unroll
                for (int rg = 0; rg < 4; rg++)
                    if (vld[rg]) Yout[(size_t)tk[rg] * NDIM + col] = acc[mf][nf][rg];
            }
        }
    }
}

extern "C" void kernel_launch(void* const* d_in, const int* in_sizes, int n_in,
                              void* d_out, int out_size, void* d_ws, size_t ws_size,
                              hipStream_t stream)
{
    const float* x    = (const float*)d_in[0];
    const float* wr   = (const float*)d_in[1];
    const float* A_fc = (const float*)d_in[2];
    const float* S_fc = (const float*)d_in[3];
    const float* A_pj = (const float*)d_in[4];
    const float* S_pj = (const float*)d_in[5];
    float* out = (float*)d_out;
    char* ws = (char*)d_ws;

    ushort* Wfc   = (ushort*)(ws + OFF_WFC);
    ushort* Wpj   = (ushort*)(ws + OFF_WPROJ);
    ushort* xb    = (ushort*)(ws + OFF_XB);
    ushort* h     = (ushort*)(ws + OFF_H);
    double* bsum  = (double*)(ws + OFF_BSUM);
    int*    eidx  = (int*)(ws + OFF_EIDX);
    int*    tok   = (int*)(ws + OFF_TOK);
    int*    counts  = (int*)(ws + OFF_CNT);
    int*    offsets = counts + 16;

    router_k<<<T_TOK / 4, 256, 0, stream>>>(x, wr, bsum, eidx, xb);
    plan_k<<<1, 256, 0, stream>>>(bsum, eidx, counts, offsets, tok,
                                  out + (size_t)T_TOK * DIM);
    wmat_k<<<10240, 256, 0, stream>>>(A_fc, S_fc, A_pj, S_pj, Wfc, Wpj);
    // fc: 40 m-tiles (BM=128) x 16 n-panels -> 640 blocks, indirect A
    moe_gemm_k<1024, 4096, 128, true><<<640, 256, 0, stream>>>(xb, Wfc, h, nullptr, counts, offsets, tok);
    // proj: 80 m-slots (BM=64) x 4 n-panels -> 320 blocks, direct scatter
    moe_gemm_k<4096, 1024, 64, false><<<320, 256, 0, stream>>>(h, Wpj, nullptr, out, counts, offsets, tok);
}

// Round 8
// 193.967 us; speedup vs baseline: 1.1837x; 1.0068x over previous
//
#include <hip/hip_runtime.h>
#include <hip/hip_bf16.h>

// MoE PHM MLP, MI355X. B=2,S=2048,D=1024 -> T=4096 tokens; E=8, N=4, HID=4096.
// Launch chain (serial stream, fused to keep the GPU fed):
//   memset(out)                                  [async, tiny]
//   front_k : router (f64 logits, argmax, bf16 x-copy, prob partial sums)
//             + W_fc materialization             [independent work fused]
//   plan_k  : histogram, stable rank, offsets, aux_loss
//   mid_k   : fc GEMM (128x256, indirect A via tok[], leaky(0.5)^2 -> h bf16)
//             + W_proj materialization           [streams under the GEMM]
//   proj_k  : proj GEMM (128x256, split-K=2), epilogue unsafeAtomicAdd into
//             out (exactly 2 commutative f32 adds per element -> deterministic,
//             bit-equal to the old partials+reduce path)
// GEMMs: m97 2-barrier single-buffer structure, XOR-swizzled LDS via
// pre-swizzled global source (measured 0 bank conflicts), XCD-aware decode.
//
// Workspace (~187 MiB):
//   [0,64MiB)    W_fc bf16 [E][4096][1024]
//   [64,128MiB)  W_proj bf16 [E][1024][4096]
//   xb bf16 [4096][1024], h bf16 [5120][4096], bsum f64[1024][8],
//   eidx int[T], tok int[5120], counts/offsets

#define T_TOK 4096
#define DIM   1024
#define NEXP  8
#define HIDD  4096
#define SLOTS 5120

static constexpr size_t OFF_WFC   = 0;
static constexpr size_t OFF_WPROJ = 67108864ull;
static constexpr size_t OFF_XB    = 134217728ull;
static constexpr size_t OFF_H     = 144703488ull;
static constexpr size_t OFF_BSUM  = 186646528ull;                     // 64 KB
static constexpr size_t OFF_EIDX  = OFF_BSUM + 1024*8*8;
static constexpr size_t OFF_TOK   = OFF_EIDX + (size_t)T_TOK*4;
static constexpr size_t OFF_CNT   = OFF_TOK + (size_t)SLOTS*4;

typedef __attribute__((ext_vector_type(8))) short short8;
typedef __attribute__((ext_vector_type(4))) float f32x4;

static __device__ __forceinline__ ushort f2bf(float f) {
    __hip_bfloat16 h = __float2bfloat16(f);
    return __builtin_bit_cast(ushort, h);
}

static __device__ __forceinline__ void gload_lds16(const ushort* g, ushort* l) {
    __builtin_amdgcn_global_load_lds((const __attribute__((address_space(1))) void*)g,
                                     (__attribute__((address_space(3))) void*)l,
                                     16, 0, 0);
}

// ---- front: blocks [0,1024) = router, [1024,9216) = W_fc materialization ----
__global__ __launch_bounds__(256) void front_k(const float* __restrict__ x,
                                               const float* __restrict__ wr,
                                               double* __restrict__ bsum,
                                               int* __restrict__ eidx,
                                               ushort* __restrict__ xb,
                                               const float* __restrict__ Afc,
                                               const float* __restrict__ Sfc,
                                               ushort* __restrict__ Wfc)
{
    __shared__ double shp[4][8];
    __shared__ float Ash[64];
    int tid = threadIdx.x;
    if (blockIdx.x < 1024) {
        // ---------------- router ----------------
        int w = tid >> 6, lane = tid & 63;
        int t = blockIdx.x * 4 + w;
        const float4* xr = (const float4*)(x + (size_t)t * DIM);
        float4 xv[4];
#pragma unroll
        for (int q = 0; q < 4; q++) xv[q] = xr[q * 64 + lane];
        ushort4* xo = (ushort4*)(xb + (size_t)t * DIM);
#pragma unroll
        for (int q = 0; q < 4; q++) {
            float4 v = xv[q];
            ushort4 bq;
            bq.x = f2bf(v.x); bq.y = f2bf(v.y); bq.z = f2bf(v.z); bq.w = f2bf(v.w);
            xo[q * 64 + lane] = bq;
        }
        double lg[8];
#pragma unroll
        for (int e = 0; e < 8; e++) {
            const float4* wv = (const float4*)(wr + (size_t)e * DIM);
            double s = 0.0;
#pragma unroll
            for (int q = 0; q < 4; q++) {
                float4 a = xv[q], b = wv[q * 64 + lane];
                s += (double)a.x * b.x + (double)a.y * b.y + (double)a.z * b.z + (double)a.w * b.w;
            }
#pragma unroll
            for (int d = 1; d < 64; d <<= 1) s += __shfl_xor(s, d);
            lg[e] = s;
        }
        double m = lg[0];
#pragma unroll
        for (int e = 1; e < 8; e++) m = lg[e] > m ? lg[e] : m;
        double ex[8], sum = 0.0;
#pragma unroll
        for (int e = 0; e < 8; e++) { ex[e] = exp(lg[e] - m); sum += ex[e]; }
        if (lane < 8) shp[w][lane] = ex[lane] / sum;
        if (lane == 0) {
            int am = 0; double bv = lg[0];
#pragma unroll
            for (int e = 1; e < 8; e++) if (lg[e] > bv) { bv = lg[e]; am = e; }  // first-max = jnp.argmax
            eidx[t] = am;
        }
        __syncthreads();
        if (tid < 8)
            bsum[(size_t)blockIdx.x * 8 + tid] =
                shp[0][tid] + shp[1][tid] + shp[2][tid] + shp[3][tid];
    } else {
        // ------------- W_fc: W[e][j*1024+o][k*256+l] = sum_i A[i,j,k]S[i,o,l]
        int b2 = blockIdx.x - 1024;
        int e = b2 >> 10, o = b2 & 1023;
        if (tid < 64) Ash[tid] = Afc[e * 64 + tid];
        __syncthreads();
        float s0 = Sfc[((size_t)(e * 4 + 0) * 1024 + o) * 256 + tid];
        float s1 = Sfc[((size_t)(e * 4 + 1) * 1024 + o) * 256 + tid];
        float s2 = Sfc[((size_t)(e * 4 + 2) * 1024 + o) * 256 + tid];
        float s3 = Sfc[((size_t)(e * 4 + 3) * 1024 + o) * 256 + tid];
        size_t base = (size_t)e * 4194304ull;
#pragma unroll
        for (int j = 0; j < 4; j++)
#pragma unroll
            for (int k = 0; k < 4; k++) {
                float v = Ash[j * 4 + k] * s0 + Ash[16 + j * 4 + k] * s1 +
                          Ash[32 + j * 4 + k] * s2 + Ash[48 + j * 4 + k] * s3;
                Wfc[base + (size_t)(j * 1024 + o) * 1024 + k * 256 + tid] = f2bf(v);
            }
    }
}

// --- plan: single block. tok=-1 init, histogram, stable rank, offsets, aux ---
__global__ __launch_bounds__(256) void plan_k(const double* __restrict__ bsum,
                                              const int* __restrict__ eidx,
                                              int* __restrict__ counts,
                                              int* __restrict__ offsets,
                                              int* __restrict__ tok,
                                              float* __restrict__ auxout)
{
    __shared__ int hist[256][8];
    __shared__ double red[256][8];
    __shared__ int offs[8];
    int tid = threadIdx.x;
    for (int i = tid; i < SLOTS; i += 256) tok[i] = -1;
    int base = tid * 16;
    int le[16];
    int lc[8] = {0,0,0,0,0,0,0,0};
#pragma unroll
    for (int j = 0; j < 16; j++) { le[j] = eidx[base + j]; lc[le[j]]++; }
#pragma unroll
    for (int e = 0; e < 8; e++) hist[tid][e] = lc[e];
    __syncthreads();
    for (int s = 1; s < 256; s <<= 1) {
        int v[8];
        if (tid >= s) {
#pragma unroll
            for (int e = 0; e < 8; e++) v[e] = hist[tid - s][e];
        }
        __syncthreads();
        if (tid >= s) {
#pragma unroll
            for (int e = 0; e < 8; e++) hist[tid][e] += v[e];
        }
        __syncthreads();
    }
    int myBase[8];
#pragma unroll
    for (int e = 0; e < 8; e++) myBase[e] = hist[tid][e] - lc[e];
    if (tid == 0) {
        int off = 0;
#pragma unroll
        for (int e = 0; e < 8; e++) {
            int c = hist[255][e];
            counts[e] = c;
            offsets[e] = off; offs[e] = off;
            off += (c + 127) & ~127;
        }
    }
    __syncthreads();
    int cur[8];
#pragma unroll
    for (int e = 0; e < 8; e++) cur[e] = myBase[e];
#pragma unroll
    for (int j = 0; j < 16; j++) {
        int e = le[j];
        tok[offs[e] + cur[e]++] = base + j;
    }
    double ps[8] = {0, 0, 0, 0, 0, 0, 0, 0};
    for (int b = tid; b < 1024; b += 256) {
#pragma unroll
        for (int e = 0; e < 8; e++) ps[e] += bsum[(size_t)b * 8 + e];
    }
#pragma unroll
    for (int e = 0; e < 8; e++) red[tid][e] = ps[e];
    __syncthreads();
    for (int s = 128; s > 0; s >>= 1) {
        if (tid < s) {
#pragma unroll
            for (int e = 0; e < 8; e++) red[tid][e] += red[tid + s][e];
        }
        __syncthreads();
    }
    if (tid == 0) {
        double aux = 0.0;
#pragma unroll
        for (int e = 0; e < 8; e++)
            aux += ((double)hist[255][e] / T_TOK) * (red[0][e] / T_TOK);
        auxout[0] = (float)(aux * NEXP);
    }
}

// ---- mid: blocks [0,640) = fc GEMM, [640,2688) = W_proj materialization ----
// fc: C=xg(tok)·W_fc^T, BM=128 BN=256 BK=64, 4 waves 2x2 (64x128 each, acc
// 4x8), m97 2-barrier single-buffer, XOR swizzle, epilogue leaky(0.5)^2 -> h.
__global__ __launch_bounds__(256, 2) void mid_k(const ushort* __restrict__ xb,
                                                const ushort* __restrict__ Wfc,
                                                ushort* __restrict__ h,
                                                const int* __restrict__ counts,
                                                const int* __restrict__ offsets,
                                                const int* __restrict__ tok,
                                                const float* __restrict__ Apj,
                                                const float* __restrict__ Spj,
                                                ushort* __restrict__ Wpj)
{
    __shared__ __align__(16) ushort As[128 * 64];
    __shared__ __align__(16) ushort Bs[256 * 64];
    __shared__ float Ashf[64];
    int b = blockIdx.x;
    int tid = threadIdx.x;
    if (b >= 640) {
        // ------ W_proj: W[e][j*256+o][k*1024+l] = sum_i A[i,j,k]S[i,o,l] -----
        int b2 = b - 640;
        int e = b2 >> 8, o = b2 & 255;
        if (tid < 64) Ashf[tid] = Apj[e * 64 + tid];
        __syncthreads();
        float s[4][4];
#pragma unroll
        for (int i = 0; i < 4; i++)
#pragma unroll
            for (int q = 0; q < 4; q++)
                s[i][q] = Spj[((size_t)(e * 4 + i) * 256 + o) * 1024 + q * 256 + tid];
        size_t base = (size_t)e * 4194304ull;
#pragma unroll
        for (int j = 0; j < 4; j++)
#pragma unroll
            for (int k = 0; k < 4; k++) {
                float a0 = Ashf[j * 4 + k], a1 = Ashf[16 + j * 4 + k];
                float a2 = Ashf[32 + j * 4 + k], a3 = Ashf[48 + j * 4 + k];
#pragma unroll
                for (int q = 0; q < 4; q++) {
                    float v = a0 * s[0][q] + a1 * s[1][q] + a2 * s[2][q] + a3 * s[3][q];
                    Wpj[base + (size_t)(j * 256 + o) * 4096 + k * 1024 + q * 256 + tid] = f2bf(v);
                }
            }
        return;
    }
    // ------------------------------ fc GEMM ---------------------------------
    constexpr int KDIM = 1024;
    constexpr int NDIM = 4096;
    int r = b >> 3;
    int nb = (b & 7) * 2 + r / 40;     // 16 n-panels, 2 per XCD
    int ms = r % 40;
    int e = -1, mt = 0, acct = 0;
#pragma unroll
    for (int i = 0; i < 8; i++) {
        int tiles = (counts[i] + 127) >> 7;
        if (e < 0 && ms < acct + tiles) { e = i; mt = ms - acct; }
        acct += tiles;
    }
    if (e < 0) return;
    int m_base = offsets[e] + mt * 128;
    int n_base = nb * 256;
    int w = tid >> 6, lane = tid & 63;
    int wm = w >> 1, wn = w & 1;
    const ushort* Bb = Wfc + (size_t)e * NDIM * KDIM + (size_t)n_base * KDIM;
    int lr = lane >> 3;                        // staging row within 8-row group
    int lcs = (((lane & 7) ^ lr) << 3);        // swizzled source chunk (ushorts)
    const ushort* arow[4];
#pragma unroll
    for (int i = 0; i < 4; i++) {
        int sl = m_base + i * 32 + w * 8 + lr;
        int rt = tok[sl]; if (rt < 0) rt = 0;
        arow[i] = xb + (size_t)rt * KDIM + lcs;
    }
    f32x4 acc[4][8];
#pragma unroll
    for (int i = 0; i < 4; i++)
#pragma unroll
        for (int j = 0; j < 8; j++) acc[i][j] = (f32x4){0.f, 0.f, 0.f, 0.f};

    for (int t = 0; t < KDIM / 64; t++) {
        int k0 = t * 64;
#pragma unroll
        for (int i = 0; i < 4; i++)
            gload_lds16(arow[i] + k0, &As[(i * 32 + w * 8) * 64]);
#pragma unroll
        for (int i = 0; i < 8; i++) {
            int r0 = i * 32 + w * 8;
            gload_lds16(Bb + (size_t)(r0 + lr) * KDIM + k0 + lcs, &Bs[r0 * 64]);
        }
        __syncthreads();
#pragma unroll
        for (int ks = 0; ks < 2; ks++) {
            short8 a[4], bfr[8];
            int ca = (((ks * 4 + (lane >> 4)) ^ (lane & 7)) << 3);
#pragma unroll
            for (int f = 0; f < 4; f++)
                a[f] = *(const short8*)&As[(wm * 64 + f * 16 + (lane & 15)) * 64 + ca];
#pragma unroll
            for (int f = 0; f < 8; f++)
                bfr[f] = *(const short8*)&Bs[(wn * 128 + f * 16 + (lane & 15)) * 64 + ca];
#pragma unroll
            for (int mf = 0; mf < 4; mf++)
#pragma unroll
                for (int nf = 0; nf < 8; nf++)
                    acc[mf][nf] = __builtin_amdgcn_mfma_f32_16x16x32_bf16(a[mf], bfr[nf], acc[mf][nf], 0, 0, 0);
        }
        __syncthreads();
    }

    int col0 = n_base + wn * 128;
    int row0 = wm * 64 + (lane >> 4) * 4;   // C/D: col=lane&15, row=(lane>>4)*4+reg
#pragma unroll
    for (int mf = 0; mf < 4; mf++)
#pragma unroll
        for (int nf = 0; nf < 8; nf++) {
            int col = col0 + nf * 16 + (lane & 15);
#pragma unroll
            for (int rg = 0; rg < 4; rg++) {
                float v = acc[mf][nf][rg];
                v = v >= 0.f ? v : 0.5f * v;   // leaky relu slope 0.5
                v = v * v;                     // square
                h[(size_t)(m_base + row0 + mf * 16 + rg) * NDIM + col] = f2bf(v);
            }
        }
}

// --- proj GEMM: BM=128 BN=256 BK=64, split-K=2, m97 structure, XOR swizzle.
// Epilogue: unsafeAtomicAdd into zeroed out[tok[slot]] (2 adds/elem, commut.)
__global__ __launch_bounds__(256, 2) void proj_k(const ushort* __restrict__ h,
                                                 const ushort* __restrict__ Wpj,
                                                 float* __restrict__ out,
                                                 const int* __restrict__ counts,
                                                 const int* __restrict__ offsets,
                                                 const int* __restrict__ tok)
{
    __shared__ __align__(16) ushort As[128 * 64];
    __shared__ __align__(16) ushort Bs[256 * 64];
    constexpr int KDIM = 4096;
    constexpr int NDIM = 1024;
    constexpr int KSUB = 2048;
    int b = blockIdx.x;                 // 320: 4 n-panels x 2 splits x 40 m
    int nb = (b & 7) >> 1;
    int split = b & 1;
    int ms = b >> 3;
    int e = -1, mt = 0, acct = 0;
#pragma unroll
    for (int i = 0; i < 8; i++) {
        int tiles = (counts[i] + 127) >> 7;
        if (e < 0 && ms < acct + tiles) { e = i; mt = ms - acct; }
        acct += tiles;
    }
    if (e < 0) return;
    int m_base = offsets[e] + mt * 128;
    int n_base = nb * 256;
    int tid = threadIdx.x, w = tid >> 6, lane = tid & 63;
    int wm = w >> 1, wn = w & 1;
    int lr = lane >> 3;
    int lcs = (((lane & 7) ^ lr) << 3);
    int kbase = split * KSUB;
    const ushort* Bb = Wpj + (size_t)e * NDIM * KDIM + (size_t)n_base * KDIM + kbase;
    const ushort* arow[4];
#pragma unroll
    for (int i = 0; i < 4; i++)
        arow[i] = h + (size_t)(m_base + i * 32 + w * 8 + lr) * KDIM + kbase + lcs;
    f32x4 acc[4][8];
#pragma unroll
    for (int i = 0; i < 4; i++)
#pragma unroll
        for (int j = 0; j < 8; j++) acc[i][j] = (f32x4){0.f, 0.f, 0.f, 0.f};

    for (int t = 0; t < KSUB / 64; t++) {
        int k0 = t * 64;
#pragma unroll
        for (int i = 0; i < 4; i++)
            gload_lds16(arow[i] + k0, &As[(i * 32 + w * 8) * 64]);
#pragma unroll
        for (int i = 0; i < 8; i++) {
            int r0 = i * 32 + w * 8;
            gload_lds16(Bb + (size_t)(r0 + lr) * KDIM + k0 + lcs, &Bs[r0 * 64]);
        }
        __syncthreads();
#pragma unroll
        for (int ks = 0; ks < 2; ks++) {
            short8 a[4], bfr[8];
            int ca = (((ks * 4 + (lane >> 4)) ^ (lane & 7)) << 3);
#pragma unroll
            for (int f = 0; f < 4; f++)
                a[f] = *(const short8*)&As[(wm * 64 + f * 16 + (lane & 15)) * 64 + ca];
#pragma unroll
            for (int f = 0; f < 8; f++)
                bfr[f] = *(const short8*)&Bs[(wn * 128 + f * 16 + (lane & 15)) * 64 + ca];
#pragma unroll
            for (int mf = 0; mf < 4; mf++)
#pragma unroll
                for (int nf = 0; nf < 8; nf++)
                    acc[mf][nf] = __builtin_amdgcn_mfma_f32_16x16x32_bf16(a[mf], bfr[nf], acc[mf][nf], 0, 0, 0);
        }
        __syncthreads();
    }

    int col0 = n_base + wn * 128;
    int row0 = wm * 64 + (lane >> 4) * 4;
    int limit = offsets[e] + counts[e];
#pragma unroll
    for (int mf = 0; mf < 4; mf++) {
        int tk[4]; bool vld[4];
#pragma unroll
        for (int rg = 0; rg < 4; rg++) {
            int slot = m_base + row0 + mf * 16 + rg;
            vld[rg] = slot < limit;
            tk[rg] = vld[rg] ? tok[slot] : 0;
        }
#pragma unroll
        for (int nf = 0; nf < 8; nf++) {
            int col = col0 + nf * 16 + (lane & 15);
#pragma unroll
            for (int rg = 0; rg < 4; rg++)
                if (vld[rg]) unsafeAtomicAdd(&out[(size_t)tk[rg] * NDIM + col], acc[mf][nf][rg]);
        }
    }
}

extern "C" void kernel_launch(void* const* d_in, const int* in_sizes, int n_in,
                              void* d_out, int out_size, void* d_ws, size_t ws_size,
                              hipStream_t stream)
{
    const float* x    = (const float*)d_in[0];
    const float* wr   = (const float*)d_in[1];
    const float* A_fc = (const float*)d_in[2];
    const float* S_fc = (const float*)d_in[3];
    const float* A_pj = (const float*)d_in[4];
    const float* S_pj = (const float*)d_in[5];
    float* out = (float*)d_out;
    char* ws = (char*)d_ws;

    ushort* Wfc   = (ushort*)(ws + OFF_WFC);
    ushort* Wpj   = (ushort*)(ws + OFF_WPROJ);
    ushort* xb    = (ushort*)(ws + OFF_XB);
    ushort* h     = (ushort*)(ws + OFF_H);
    double* bsum  = (double*)(ws + OFF_BSUM);
    int*    eidx  = (int*)(ws + OFF_EIDX);
    int*    tok   = (int*)(ws + OFF_TOK);
    int*    counts  = (int*)(ws + OFF_CNT);
    int*    offsets = counts + 16;

    // zero out for the proj atomic accumulation (aux slot at T*D untouched)
    hipMemsetAsync(out, 0, (size_t)T_TOK * DIM * sizeof(float), stream);
    front_k<<<1024 + 8192, 256, 0, stream>>>(x, wr, bsum, eidx, xb, A_fc, S_fc, Wfc);
    plan_k<<<1, 256, 0, stream>>>(bsum, eidx, counts, offsets, tok,
                                  out + (size_t)T_TOK * DIM);
    mid_k<<<640 + 2048, 256, 0, stream>>>(xb, Wfc, h, counts, offsets, tok,
                                          A_pj, S_pj, Wpj);
    proj_k<<<320, 256, 0, stream>>>(h, Wpj, out, counts, offsets, tok);
}

// Round 9
// 178.091 us; speedup vs baseline: 1.2892x; 1.0891x over previous
//
#include <hip/hip_runtime.h>
#include <hip/hip_bf16.h>

// MoE PHM MLP, MI355X. B=2,S=2048,D=1024 -> T=4096 tokens; E=8, N=4, HID=4096.
// Launch chain:
//   front_k : router (f64 logits, argmax, bf16 x-copy, prob partial sums)
//             + W_fc materialization          [independent work fused]
//   plan_k  : histogram, stable rank, offsets, aux_loss
//   mid_k   : fc GEMM (128x256, indirect A via tok[], leaky(0.5)^2 -> h bf16)
//             + W_proj materialization        [streams under the GEMM]
//   proj_k  : proj GEMM (128x256, split-K=2) -> f32 partials (aliased onto
//             dead W_fc region)
//   reduce_k: out[tok[slot]] = P0[slot] + P1[slot]
// GEMMs: m97 2-barrier single-buffer structure, XOR-swizzled LDS via
// pre-swizzled global source (measured 0 bank conflicts), XCD-aware decode.
//
// Workspace (~187 MiB):
//   [0,64MiB)    W_fc bf16 [E][4096][1024]; dead after mid_k -> proj partials
//                P[2][5120][1024] f32 (42 MiB)
//   [64,128MiB)  W_proj bf16 [E][1024][4096]
//   xb bf16 [4096][1024], h bf16 [5120][4096], bsum f64[1024][8],
//   eidx int[T], tok int[5120], counts/offsets

#define T_TOK 4096
#define DIM   1024
#define NEXP  8
#define HIDD  4096
#define SLOTS 5120

static constexpr size_t OFF_WFC   = 0;
static constexpr size_t OFF_WPROJ = 67108864ull;
static constexpr size_t OFF_XB    = 134217728ull;
static constexpr size_t OFF_H     = 144703488ull;
static constexpr size_t OFF_BSUM  = 186646528ull;                     // 64 KB
static constexpr size_t OFF_EIDX  = OFF_BSUM + 1024*8*8;
static constexpr size_t OFF_TOK   = OFF_EIDX + (size_t)T_TOK*4;
static constexpr size_t OFF_CNT   = OFF_TOK + (size_t)SLOTS*4;

typedef __attribute__((ext_vector_type(8))) short short8;
typedef __attribute__((ext_vector_type(4))) float f32x4;

static __device__ __forceinline__ ushort f2bf(float f) {
    __hip_bfloat16 h = __float2bfloat16(f);
    return __builtin_bit_cast(ushort, h);
}

static __device__ __forceinline__ void gload_lds16(const ushort* g, ushort* l) {
    __builtin_amdgcn_global_load_lds((const __attribute__((address_space(1))) void*)g,
                                     (__attribute__((address_space(3))) void*)l,
                                     16, 0, 0);
}

// ---- front: blocks [0,1024) = router, [1024,9216) = W_fc materialization ----
__global__ __launch_bounds__(256) void front_k(const float* __restrict__ x,
                                               const float* __restrict__ wr,
                                               double* __restrict__ bsum,
                                               int* __restrict__ eidx,
                                               ushort* __restrict__ xb,
                                               const float* __restrict__ Afc,
                                               const float* __restrict__ Sfc,
                                               ushort* __restrict__ Wfc)
{
    __shared__ double shp[4][8];
    __shared__ float Ash[64];
    int tid = threadIdx.x;
    if (blockIdx.x < 1024) {
        // ---------------- router ----------------
        int w = tid >> 6, lane = tid & 63;
        int t = blockIdx.x * 4 + w;
        const float4* xr = (const float4*)(x + (size_t)t * DIM);
        float4 xv[4];
#pragma unroll
        for (int q = 0; q < 4; q++) xv[q] = xr[q * 64 + lane];
        ushort4* xo = (ushort4*)(xb + (size_t)t * DIM);
#pragma unroll
        for (int q = 0; q < 4; q++) {
            float4 v = xv[q];
            ushort4 bq;
            bq.x = f2bf(v.x); bq.y = f2bf(v.y); bq.z = f2bf(v.z); bq.w = f2bf(v.w);
            xo[q * 64 + lane] = bq;
        }
        double lg[8];
#pragma unroll
        for (int e = 0; e < 8; e++) {
            const float4* wv = (const float4*)(wr + (size_t)e * DIM);
            double s = 0.0;
#pragma unroll
            for (int q = 0; q < 4; q++) {
                float4 a = xv[q], b = wv[q * 64 + lane];
                s += (double)a.x * b.x + (double)a.y * b.y + (double)a.z * b.z + (double)a.w * b.w;
            }
#pragma unroll
            for (int d = 1; d < 64; d <<= 1) s += __shfl_xor(s, d);
            lg[e] = s;
        }
        double m = lg[0];
#pragma unroll
        for (int e = 1; e < 8; e++) m = lg[e] > m ? lg[e] : m;
        double ex[8], sum = 0.0;
#pragma unroll
        for (int e = 0; e < 8; e++) { ex[e] = exp(lg[e] - m); sum += ex[e]; }
        if (lane < 8) shp[w][lane] = ex[lane] / sum;
        if (lane == 0) {
            int am = 0; double bv = lg[0];
#pragma unroll
            for (int e = 1; e < 8; e++) if (lg[e] > bv) { bv = lg[e]; am = e; }  // first-max = jnp.argmax
            eidx[t] = am;
        }
        __syncthreads();
        if (tid < 8)
            bsum[(size_t)blockIdx.x * 8 + tid] =
                shp[0][tid] + shp[1][tid] + shp[2][tid] + shp[3][tid];
    } else {
        // ------------- W_fc: W[e][j*1024+o][k*256+l] = sum_i A[i,j,k]S[i,o,l]
        int b2 = blockIdx.x - 1024;
        int e = b2 >> 10, o = b2 & 1023;
        if (tid < 64) Ash[tid] = Afc[e * 64 + tid];
        __syncthreads();
        float s0 = Sfc[((size_t)(e * 4 + 0) * 1024 + o) * 256 + tid];
        float s1 = Sfc[((size_t)(e * 4 + 1) * 1024 + o) * 256 + tid];
        float s2 = Sfc[((size_t)(e * 4 + 2) * 1024 + o) * 256 + tid];
        float s3 = Sfc[((size_t)(e * 4 + 3) * 1024 + o) * 256 + tid];
        size_t base = (size_t)e * 4194304ull;
#pragma unroll
        for (int j = 0; j < 4; j++)
#pragma unroll
            for (int k = 0; k < 4; k++) {
                float v = Ash[j * 4 + k] * s0 + Ash[16 + j * 4 + k] * s1 +
                          Ash[32 + j * 4 + k] * s2 + Ash[48 + j * 4 + k] * s3;
                Wfc[base + (size_t)(j * 1024 + o) * 1024 + k * 256 + tid] = f2bf(v);
            }
    }
}

// --- plan: single block. tok=-1 init, histogram, stable rank, offsets, aux ---
__global__ __launch_bounds__(256) void plan_k(const double* __restrict__ bsum,
                                              const int* __restrict__ eidx,
                                              int* __restrict__ counts,
                                              int* __restrict__ offsets,
                                              int* __restrict__ tok,
                                              float* __restrict__ auxout)
{
    __shared__ int hist[256][8];
    __shared__ double red[256][8];
    __shared__ int offs[8];
    int tid = threadIdx.x;
    for (int i = tid; i < SLOTS; i += 256) tok[i] = -1;
    int base = tid * 16;
    int le[16];
    int lc[8] = {0,0,0,0,0,0,0,0};
#pragma unroll
    for (int j = 0; j < 16; j++) { le[j] = eidx[base + j]; lc[le[j]]++; }
#pragma unroll
    for (int e = 0; e < 8; e++) hist[tid][e] = lc[e];
    __syncthreads();
    for (int s = 1; s < 256; s <<= 1) {
        int v[8];
        if (tid >= s) {
#pragma unroll
            for (int e = 0; e < 8; e++) v[e] = hist[tid - s][e];
        }
        __syncthreads();
        if (tid >= s) {
#pragma unroll
            for (int e = 0; e < 8; e++) hist[tid][e] += v[e];
        }
        __syncthreads();
    }
    int myBase[8];
#pragma unroll
    for (int e = 0; e < 8; e++) myBase[e] = hist[tid][e] - lc[e];
    if (tid == 0) {
        int off = 0;
#pragma unroll
        for (int e = 0; e < 8; e++) {
            int c = hist[255][e];
            counts[e] = c;
            offsets[e] = off; offs[e] = off;
            off += (c + 127) & ~127;
        }
    }
    __syncthreads();
    int cur[8];
#pragma unroll
    for (int e = 0; e < 8; e++) cur[e] = myBase[e];
#pragma unroll
    for (int j = 0; j < 16; j++) {
        int e = le[j];
        tok[offs[e] + cur[e]++] = base + j;
    }
    double ps[8] = {0, 0, 0, 0, 0, 0, 0, 0};
    for (int b = tid; b < 1024; b += 256) {
#pragma unroll
        for (int e = 0; e < 8; e++) ps[e] += bsum[(size_t)b * 8 + e];
    }
#pragma unroll
    for (int e = 0; e < 8; e++) red[tid][e] = ps[e];
    __syncthreads();
    for (int s = 128; s > 0; s >>= 1) {
        if (tid < s) {
#pragma unroll
            for (int e = 0; e < 8; e++) red[tid][e] += red[tid + s][e];
        }
        __syncthreads();
    }
    if (tid == 0) {
        double aux = 0.0;
#pragma unroll
        for (int e = 0; e < 8; e++)
            aux += ((double)hist[255][e] / T_TOK) * (red[0][e] / T_TOK);
        auxout[0] = (float)(aux * NEXP);
    }
}

// ---- mid: blocks [0,640) = fc GEMM, [640,2688) = W_proj materialization ----
// fc: C=xb(tok)·W_fc^T, BM=128 BN=256 BK=64, 4 waves 2x2 (64x128 each, acc
// 4x8), m97 2-barrier single-buffer, XOR swizzle, epilogue leaky(0.5)^2 -> h.
__global__ __launch_bounds__(256, 2) void mid_k(const ushort* __restrict__ xb,
                                                const ushort* __restrict__ Wfc,
                                                ushort* __restrict__ h,
                                                const int* __restrict__ counts,
                                                const int* __restrict__ offsets,
                                                const int* __restrict__ tok,
                                                const float* __restrict__ Apj,
                                                const float* __restrict__ Spj,
                                                ushort* __restrict__ Wpj)
{
    __shared__ __align__(16) ushort As[128 * 64];
    __shared__ __align__(16) ushort Bs[256 * 64];
    __shared__ float Ashf[64];
    int b = blockIdx.x;
    int tid = threadIdx.x;
    if (b >= 640) {
        // ------ W_proj: W[e][j*256+o][k*1024+l] = sum_i A[i,j,k]S[i,o,l] -----
        int b2 = b - 640;
        int e = b2 >> 8, o = b2 & 255;
        if (tid < 64) Ashf[tid] = Apj[e * 64 + tid];
        __syncthreads();
        float s[4][4];
#pragma unroll
        for (int i = 0; i < 4; i++)
#pragma unroll
            for (int q = 0; q < 4; q++)
                s[i][q] = Spj[((size_t)(e * 4 + i) * 256 + o) * 1024 + q * 256 + tid];
        size_t base = (size_t)e * 4194304ull;
#pragma unroll
        for (int j = 0; j < 4; j++)
#pragma unroll
            for (int k = 0; k < 4; k++) {
                float a0 = Ashf[j * 4 + k], a1 = Ashf[16 + j * 4 + k];
                float a2 = Ashf[32 + j * 4 + k], a3 = Ashf[48 + j * 4 + k];
#pragma unroll
                for (int q = 0; q < 4; q++) {
                    float v = a0 * s[0][q] + a1 * s[1][q] + a2 * s[2][q] + a3 * s[3][q];
                    Wpj[base + (size_t)(j * 256 + o) * 4096 + k * 1024 + q * 256 + tid] = f2bf(v);
                }
            }
        return;
    }
    // ------------------------------ fc GEMM ---------------------------------
    constexpr int KDIM = 1024;
    constexpr int NDIM = 4096;
    int r = b >> 3;
    int nb = (b & 7) * 2 + r / 40;     // 16 n-panels, 2 per XCD
    int ms = r % 40;
    int e = -1, mt = 0, acct = 0;
#pragma unroll
    for (int i = 0; i < 8; i++) {
        int tiles = (counts[i] + 127) >> 7;
        if (e < 0 && ms < acct + tiles) { e = i; mt = ms - acct; }
        acct += tiles;
    }
    if (e < 0) return;
    int m_base = offsets[e] + mt * 128;
    int n_base = nb * 256;
    int w = tid >> 6, lane = tid & 63;
    int wm = w >> 1, wn = w & 1;
    const ushort* Bb = Wfc + (size_t)e * NDIM * KDIM + (size_t)n_base * KDIM;
    int lr = lane >> 3;                        // staging row within 8-row group
    int lcs = (((lane & 7) ^ lr) << 3);        // swizzled source chunk (ushorts)
    const ushort* arow[4];
#pragma unroll
    for (int i = 0; i < 4; i++) {
        int sl = m_base + i * 32 + w * 8 + lr;
        int rt = tok[sl]; if (rt < 0) rt = 0;
        arow[i] = xb + (size_t)rt * KDIM + lcs;
    }
    f32x4 acc[4][8];
#pragma unroll
    for (int i = 0; i < 4; i++)
#pragma unroll
        for (int j = 0; j < 8; j++) acc[i][j] = (f32x4){0.f, 0.f, 0.f, 0.f};

    for (int t = 0; t < KDIM / 64; t++) {
        int k0 = t * 64;
#pragma unroll
        for (int i = 0; i < 4; i++)
            gload_lds16(arow[i] + k0, &As[(i * 32 + w * 8) * 64]);
#pragma unroll
        for (int i = 0; i < 8; i++) {
            int r0 = i * 32 + w * 8;
            gload_lds16(Bb + (size_t)(r0 + lr) * KDIM + k0 + lcs, &Bs[r0 * 64]);
        }
        __syncthreads();
#pragma unroll
        for (int ks = 0; ks < 2; ks++) {
            short8 a[4], bfr[8];
            int ca = (((ks * 4 + (lane >> 4)) ^ (lane & 7)) << 3);
#pragma unroll
            for (int f = 0; f < 4; f++)
                a[f] = *(const short8*)&As[(wm * 64 + f * 16 + (lane & 15)) * 64 + ca];
#pragma unroll
            for (int f = 0; f < 8; f++)
                bfr[f] = *(const short8*)&Bs[(wn * 128 + f * 16 + (lane & 15)) * 64 + ca];
#pragma unroll
            for (int mf = 0; mf < 4; mf++)
#pragma unroll
                for (int nf = 0; nf < 8; nf++)
                    acc[mf][nf] = __builtin_amdgcn_mfma_f32_16x16x32_bf16(a[mf], bfr[nf], acc[mf][nf], 0, 0, 0);
        }
        __syncthreads();
    }

    int col0 = n_base + wn * 128;
    int row0 = wm * 64 + (lane >> 4) * 4;   // C/D: col=lane&15, row=(lane>>4)*4+reg
#pragma unroll
    for (int mf = 0; mf < 4; mf++)
#pragma unroll
        for (int nf = 0; nf < 8; nf++) {
            int col = col0 + nf * 16 + (lane & 15);
#pragma unroll
            for (int rg = 0; rg < 4; rg++) {
                float v = acc[mf][nf][rg];
                v = v >= 0.f ? v : 0.5f * v;   // leaky relu slope 0.5
                v = v * v;                     // square
                h[(size_t)(m_base + row0 + mf * 16 + rg) * NDIM + col] = f2bf(v);
            }
        }
}

// --- proj GEMM: BM=128 BN=256 BK=64, split-K=2, m97 structure, XOR swizzle.
// Writes f32 partials P[split][slot][col] (r5-proven config).
__global__ __launch_bounds__(256, 2) void proj_k(const ushort* __restrict__ h,
                                                 const ushort* __restrict__ Wpj,
                                                 float* __restrict__ Part,
                                                 const int* __restrict__ counts,
                                                 const int* __restrict__ offsets)
{
    __shared__ __align__(16) ushort As[128 * 64];
    __shared__ __align__(16) ushort Bs[256 * 64];
    constexpr int KDIM = 4096;
    constexpr int NDIM = 1024;
    constexpr int KSUB = 2048;
    int b = blockIdx.x;                 // 320: 4 n-panels x 2 splits x 40 m
    int nb = (b & 7) >> 1;
    int split = b & 1;
    int ms = b >> 3;
    int e = -1, mt = 0, acct = 0;
#pragma unroll
    for (int i = 0; i < 8; i++) {
        int tiles = (counts[i] + 127) >> 7;
        if (e < 0 && ms < acct + tiles) { e = i; mt = ms - acct; }
        acct += tiles;
    }
    if (e < 0) return;
    int m_base = offsets[e] + mt * 128;
    int n_base = nb * 256;
    int tid = threadIdx.x, w = tid >> 6, lane = tid & 63;
    int wm = w >> 1, wn = w & 1;
    int lr = lane >> 3;
    int lcs = (((lane & 7) ^ lr) << 3);
    int kbase = split * KSUB;
    const ushort* Bb = Wpj + (size_t)e * NDIM * KDIM + (size_t)n_base * KDIM + kbase;
    const ushort* arow[4];
#pragma unroll
    for (int i = 0; i < 4; i++)
        arow[i] = h + (size_t)(m_base + i * 32 + w * 8 + lr) * KDIM + kbase + lcs;
    f32x4 acc[4][8];
#pragma unroll
    for (int i = 0; i < 4; i++)
#pragma unroll
        for (int j = 0; j < 8; j++) acc[i][j] = (f32x4){0.f, 0.f, 0.f, 0.f};

    for (int t = 0; t < KSUB / 64; t++) {
        int k0 = t * 64;
#pragma unroll
        for (int i = 0; i < 4; i++)
            gload_lds16(arow[i] + k0, &As[(i * 32 + w * 8) * 64]);
#pragma unroll
        for (int i = 0; i < 8; i++) {
            int r0 = i * 32 + w * 8;
            gload_lds16(Bb + (size_t)(r0 + lr) * KDIM + k0 + lcs, &Bs[r0 * 64]);
        }
        __syncthreads();
#pragma unroll
        for (int ks = 0; ks < 2; ks++) {
            short8 a[4], bfr[8];
            int ca = (((ks * 4 + (lane >> 4)) ^ (lane & 7)) << 3);
#pragma unroll
            for (int f = 0; f < 4; f++)
                a[f] = *(const short8*)&As[(wm * 64 + f * 16 + (lane & 15)) * 64 + ca];
#pragma unroll
            for (int f = 0; f < 8; f++)
                bfr[f] = *(const short8*)&Bs[(wn * 128 + f * 16 + (lane & 15)) * 64 + ca];
#pragma unroll
            for (int mf = 0; mf < 4; mf++)
#pragma unroll
                for (int nf = 0; nf < 8; nf++)
                    acc[mf][nf] = __builtin_amdgcn_mfma_f32_16x16x32_bf16(a[mf], bfr[nf], acc[mf][nf], 0, 0, 0);
        }
        __syncthreads();
    }

    float* P = Part + (size_t)split * SLOTS * NDIM;
    int col0 = n_base + wn * 128;
    int row0 = wm * 64 + (lane >> 4) * 4;
#pragma unroll
    for (int mf = 0; mf < 4; mf++)
#pragma unroll
        for (int nf = 0; nf < 8; nf++) {
            int col = col0 + nf * 16 + (lane & 15);
#pragma unroll
            for (int rg = 0; rg < 4; rg++)
                P[(size_t)(m_base + row0 + mf * 16 + rg) * NDIM + col] = acc[mf][nf][rg];
        }
}

// -------- reduce: out[tok[slot]] = P0[slot] + P1[slot] (valid slots) ---------
__global__ __launch_bounds__(256) void reduce_k(const float* __restrict__ P,
                                                const int* __restrict__ tok,
                                                float* __restrict__ out)
{
    int slot = blockIdx.x;
    int t = tok[slot];
    if (t < 0) return;
    const float4* p0 = (const float4*)(P + (size_t)slot * DIM);
    const float4* p1 = (const float4*)(P + (size_t)(SLOTS + slot) * DIM);
    float4* o = (float4*)(out + (size_t)t * DIM);
    int i = threadIdx.x;
    float4 a = p0[i], b = p1[i];
    o[i] = (float4){a.x + b.x, a.y + b.y, a.z + b.z, a.w + b.w};
}

extern "C" void kernel_launch(void* const* d_in, const int* in_sizes, int n_in,
                              void* d_out, int out_size, void* d_ws, size_t ws_size,
                              hipStream_t stream)
{
    const float* x    = (const float*)d_in[0];
    const float* wr   = (const float*)d_in[1];
    const float* A_fc = (const float*)d_in[2];
    const float* S_fc = (const float*)d_in[3];
    const float* A_pj = (const float*)d_in[4];
    const float* S_pj = (const float*)d_in[5];
    float* out = (float*)d_out;
    char* ws = (char*)d_ws;

    ushort* Wfc   = (ushort*)(ws + OFF_WFC);
    float*  Part  = (float*)(ws + OFF_WFC);    // aliases W_fc (dead after mid_k)
    ushort* Wpj   = (ushort*)(ws + OFF_WPROJ);
    ushort* xb    = (ushort*)(ws + OFF_XB);
    ushort* h     = (ushort*)(ws + OFF_H);
    double* bsum  = (double*)(ws + OFF_BSUM);
    int*    eidx  = (int*)(ws + OFF_EIDX);
    int*    tok   = (int*)(ws + OFF_TOK);
    int*    counts  = (int*)(ws + OFF_CNT);
    int*    offsets = counts + 16;

    front_k<<<1024 + 8192, 256, 0, stream>>>(x, wr, bsum, eidx, xb, A_fc, S_fc, Wfc);
    plan_k<<<1, 256, 0, stream>>>(bsum, eidx, counts, offsets, tok,
                                  out + (size_t)T_TOK * DIM);
    mid_k<<<640 + 2048, 256, 0, stream>>>(xb, Wfc, h, counts, offsets, tok,
                                          A_pj, S_pj, Wpj);
    proj_k<<<320, 256, 0, stream>>>(h, Wpj, Part, counts, offsets);
    reduce_k<<<SLOTS, 256, 0, stream>>>(Part, tok, out);
}